// Round 2
// baseline (1314.779 us; speedup 1.0000x reference)
//
#include <hip/hip_runtime.h>
#include <stdint.h>

#define TOKENS 8192
#define INF    4096
#define OUTF   4096
#define NT     (INF / 64)   // 64 K-tiles of BK=64

typedef __bf16 bf16x8 __attribute__((ext_vector_type(8)));
typedef float  f32x4  __attribute__((ext_vector_type(4)));
typedef unsigned short ushort_t;

// ---------- fp32 -> bf16 (RNE) ----------
__device__ __forceinline__ unsigned short f2bf(float f) {
  union { float f; unsigned int u; } v;
  v.f = f;
  unsigned int r = v.u + 0x7fffu + ((v.u >> 16) & 1u);
  return (unsigned short)(r >> 16);
}

__global__ void l2b_conv_x(const float* __restrict__ x,
                           unsigned short* __restrict__ xb, int n4) {
  int idx = blockIdx.x * blockDim.x + threadIdx.x;
  int stride = gridDim.x * blockDim.x;
  for (int i = idx; i < n4; i += stride) {
    float4 v = reinterpret_cast<const float4*>(x)[i];
    ushort4 o;
    o.x = f2bf(v.x); o.y = f2bf(v.y); o.z = f2bf(v.z); o.w = f2bf(v.w);
    reinterpret_cast<ushort4*>(xb)[i] = o;
  }
}

__global__ void l2b_conv_w(const int* __restrict__ w,
                           unsigned short* __restrict__ wb, int n4) {
  int idx = blockIdx.x * blockDim.x + threadIdx.x;
  int stride = gridDim.x * blockDim.x;
  for (int i = idx; i < n4; i += stride) {
    int4 v = reinterpret_cast<const int4*>(w)[i];
    ushort4 o;  // {-2,-1,0,1}: exact in bf16
    o.x = f2bf((float)v.x); o.y = f2bf((float)v.y);
    o.z = f2bf((float)v.z); o.w = f2bf((float)v.w);
    reinterpret_cast<ushort4*>(wb)[i] = o;
  }
}

// ---------- async global->LDS, 16B/lane (dest = wave base + lane*16) ----------
__device__ __forceinline__ void gload_lds16(const ushort_t* g, ushort_t* l) {
  auto gp = reinterpret_cast<__attribute__((address_space(1))) unsigned int*>(
      reinterpret_cast<uintptr_t>(g));
  auto lp = reinterpret_cast<__attribute__((address_space(3))) unsigned int*>(
      reinterpret_cast<uintptr_t>(l));
  __builtin_amdgcn_global_load_lds(gp, lp, 16, 0, 0);
}

// ---------- st_16x32 swizzle on byte offsets within a 16 KiB half-slot -------
__device__ __forceinline__ int swz(int b) { return b ^ (((b >> 9) & 1) << 5); }

// swizzled ds_read of one bf16x8 fragment from a [128][64] half-slot
__device__ __forceinline__ bf16x8 ldsRd(const ushort_t* slot, int row, int colb) {
  int off = (row << 7) | colb;
  off ^= ((off >> 9) & 1) << 5;
  return *reinterpret_cast<const bf16x8*>(
      reinterpret_cast<const char*>(slot) + off);
}

// stage one 128x64 half-tile: 2 gload_lds per thread; source pre-swizzled
__device__ __forceinline__ void stage_half(const ushort_t* __restrict__ G,
                                           int rowBase, int t, ushort_t* slot,
                                           int chunk0, int r0, int c0, int r1, int c1) {
  gload_lds16(G + (size_t)(rowBase + r0) * INF + t * 64 + (c0 >> 1),
              slot + chunk0 * 512);
  gload_lds16(G + (size_t)(rowBase + r1) * INF + t * 64 + (c1 >> 1),
              slot + (chunk0 + 1) * 512);
}

__device__ __forceinline__ f32x4 mfma(bf16x8 a, bf16x8 b, f32x4 c) {
  return __builtin_amdgcn_mfma_f32_16x16x32_bf16(a, b, c, 0, 0, 0);
}

template <int N>
__device__ __forceinline__ void vmwait() {
  if constexpr (N == 8)      asm volatile("s_waitcnt vmcnt(8)" ::: "memory");
  else if constexpr (N == 4) asm volatile("s_waitcnt vmcnt(4)" ::: "memory");
  else if constexpr (N == 0) asm volatile("s_waitcnt vmcnt(0)" ::: "memory");
}

// ---------------- one K-tile: 4 phases, 64 MFMA/wave ----------------
// Slot discipline (provably race-free):
//   A-slot(tile t): read ph1 (a0) + ph3 (a1); overwritten by A(t+2) issued ph4.
//   B-slot(tile t): pre-read during ph3/ph4 of tile t-1; overwritten by B(t+2)
//                   issued ph1/ph2 of tile t.
//   vmcnt(8) at ph2-end covers B(t+1) (needed ph3); at ph4-end covers A(t+1)
//   (needed ph1 of t+1). Issued->waited distance is always >= 4 phases.
template <int VM2, int VM4, bool STG, bool PRER>
__device__ __forceinline__ void ktile(
    const ushort_t* __restrict__ A, const ushort_t* __restrict__ B,
    int rowBlk, int colBlk, int t,
    ushort_t* lA0, ushort_t* lA1, ushort_t* lB0, ushort_t* lB1,
    const ushort_t* oB, const ushort_t* myA, int brow,
    bf16x8 (&bu)[4][2], bf16x8 (&br)[4][2], f32x4 (&acc)[8][4],
    int fr, int fk, int chunk0, int r0, int c0, int r1, int c1) {
  const int cb = fk * 16;
  bf16x8 a0[4][2];
  // ---- phase 1: read a0 (m0-3); stage B-half0 of t+2; MFMA a0 x bu[0,1] ----
#pragma unroll
  for (int m = 0; m < 4; ++m) {
    a0[m][0] = ldsRd(myA, m * 16 + fr, cb);
    a0[m][1] = ldsRd(myA, m * 16 + fr, 64 + cb);
  }
  if (STG) stage_half(B, colBlk + 0, t + 2, lB0, chunk0, r0, c0, r1, c1);
  __builtin_amdgcn_s_barrier();
  asm volatile("s_waitcnt lgkmcnt(0)" ::: "memory");
  __builtin_amdgcn_s_setprio(1);
#pragma unroll
  for (int m = 0; m < 4; ++m) {
    acc[m][0] = mfma(a0[m][0], bu[0][0], acc[m][0]);
    acc[m][0] = mfma(a0[m][1], bu[0][1], acc[m][0]);
    acc[m][1] = mfma(a0[m][0], bu[1][0], acc[m][1]);
    acc[m][1] = mfma(a0[m][1], bu[1][1], acc[m][1]);
  }
  __builtin_amdgcn_s_setprio(0);
  __builtin_amdgcn_s_barrier();
  // ---- phase 2: stage B-half1 of t+2; MFMA a0 x bu[2,3]; vmcnt(VM2) ----
  if (STG) stage_half(B, colBlk + 128, t + 2, lB1, chunk0, r0, c0, r1, c1);
  __builtin_amdgcn_s_barrier();
  asm volatile("s_waitcnt lgkmcnt(0)" ::: "memory");
  __builtin_amdgcn_s_setprio(1);
#pragma unroll
  for (int m = 0; m < 4; ++m) {
    acc[m][2] = mfma(a0[m][0], bu[2][0], acc[m][2]);
    acc[m][2] = mfma(a0[m][1], bu[2][1], acc[m][2]);
    acc[m][3] = mfma(a0[m][0], bu[3][0], acc[m][3]);
    acc[m][3] = mfma(a0[m][1], bu[3][1], acc[m][3]);
  }
  __builtin_amdgcn_s_setprio(0);
  vmwait<VM2>();
  __builtin_amdgcn_s_barrier();
  // ---- phase 3: read a1 (m4-7) + pre-read next b[0,1]; MFMA a1 x bu[0,1] ----
  bf16x8 a1[4][2];
#pragma unroll
  for (int m = 0; m < 4; ++m) {
    a1[m][0] = ldsRd(myA, 64 + m * 16 + fr, cb);
    a1[m][1] = ldsRd(myA, 64 + m * 16 + fr, 64 + cb);
  }
  if (PRER) {
#pragma unroll
    for (int n = 0; n < 2; ++n) {
      br[n][0] = ldsRd(oB, brow + n * 16 + fr, cb);
      br[n][1] = ldsRd(oB, brow + n * 16 + fr, 64 + cb);
    }
    asm volatile("s_waitcnt lgkmcnt(8)" ::: "memory");
  }
  __builtin_amdgcn_s_barrier();
  asm volatile("s_waitcnt lgkmcnt(0)" ::: "memory");
  __builtin_amdgcn_s_setprio(1);
#pragma unroll
  for (int m = 0; m < 4; ++m) {
    acc[4 + m][0] = mfma(a1[m][0], bu[0][0], acc[4 + m][0]);
    acc[4 + m][0] = mfma(a1[m][1], bu[0][1], acc[4 + m][0]);
    acc[4 + m][1] = mfma(a1[m][0], bu[1][0], acc[4 + m][1]);
    acc[4 + m][1] = mfma(a1[m][1], bu[1][1], acc[4 + m][1]);
  }
  __builtin_amdgcn_s_setprio(0);
  __builtin_amdgcn_s_barrier();
  // ---- phase 4: pre-read b[2,3]; stage A halves of t+2; MFMA a1 x bu[2,3] ----
  if (PRER) {
#pragma unroll
    for (int n = 2; n < 4; ++n) {
      br[n][0] = ldsRd(oB, brow + n * 16 + fr, cb);
      br[n][1] = ldsRd(oB, brow + n * 16 + fr, 64 + cb);
    }
  }
  if (STG) {
    stage_half(A, rowBlk + 0, t + 2, lA0, chunk0, r0, c0, r1, c1);
    stage_half(A, rowBlk + 128, t + 2, lA1, chunk0, r0, c0, r1, c1);
  }
  __builtin_amdgcn_s_barrier();
  asm volatile("s_waitcnt lgkmcnt(0)" ::: "memory");
  __builtin_amdgcn_s_setprio(1);
#pragma unroll
  for (int m = 0; m < 4; ++m) {
    acc[4 + m][2] = mfma(a1[m][0], bu[2][0], acc[4 + m][2]);
    acc[4 + m][2] = mfma(a1[m][1], bu[2][1], acc[4 + m][2]);
    acc[4 + m][3] = mfma(a1[m][0], bu[3][0], acc[4 + m][3]);
    acc[4 + m][3] = mfma(a1[m][1], bu[3][1], acc[4 + m][3]);
  }
  __builtin_amdgcn_s_setprio(0);
  vmwait<VM4>();
  __builtin_amdgcn_s_barrier();
}

// ---------------- 256x256 8-phase GEMM: C[t][o] = A[t][:] . B[o][:] ----------
__global__ __launch_bounds__(512, 2) void l2b_gemm8(
    const ushort_t* __restrict__ A, const ushort_t* __restrict__ B,
    const float* __restrict__ scale, const float* __restrict__ bias,
    float* __restrict__ C) {
  extern __shared__ ushort_t smem[];        // 128 KiB
  ushort_t* LA = smem;                      // 4 half-slots [128][64]
  ushort_t* LB = smem + 4 * 8192;           // 4 half-slots [128][64]

  const int tid = threadIdx.x;
  const int lane = tid & 63;
  const int wid = tid >> 6;                 // 0..7
  const int wm = wid >> 2, wn = wid & 3;    // 2x4 wave grid
  const int fr = lane & 15, fk = lane >> 4;

  // XCD-aware swizzle: nwg=512, 512%8==0
  const int bid = (int)blockIdx.x;
  const int idx = (bid & 7) * 64 + (bid >> 3);
  const int bm = idx >> 4, bn = idx & 15;   // 32 x 16 tiles
  const int rowBlk = bm * 256, colBlk = bn * 256;

  // staging source precompute: inverse-swizzled (row, colbyte) per gload op
  const int chunk0 = wid * 2;
  const int p0 = swz(chunk0 * 1024 + lane * 16);
  const int p1 = swz((chunk0 + 1) * 1024 + lane * 16);
  const int r0 = p0 >> 7, c0 = p0 & 127, r1 = p1 >> 7, c1 = p1 & 127;

  // slot pointers (parity 0 / parity 1, halves 0/1)
  ushort_t* lA0_0 = LA;              ushort_t* lA1_0 = LA + 8192;
  ushort_t* lA0_1 = LA + 2 * 8192;   ushort_t* lA1_1 = LA + 3 * 8192;
  ushort_t* lB0_0 = LB;              ushort_t* lB1_0 = LB + 8192;
  ushort_t* lB0_1 = LB + 2 * 8192;   ushort_t* lB1_1 = LB + 3 * 8192;

  const ushort_t* myA_0 = wm ? lA1_0 : lA0_0;
  const ushort_t* myA_1 = wm ? lA1_1 : lA0_1;
  const int bh = wn >> 1;
  const ushort_t* myB_0 = bh ? lB1_0 : lB0_0;
  const ushort_t* myB_1 = bh ? lB1_1 : lB0_1;
  const int brow = (wn & 1) * 64;

  // ---- prologue: stage tiles 0 and 1 (B first), wait, pre-read b of tile 0
  stage_half(B, colBlk + 0,   0, lB0_0, chunk0, r0, c0, r1, c1);
  stage_half(B, colBlk + 128, 0, lB1_0, chunk0, r0, c0, r1, c1);
  stage_half(A, rowBlk + 0,   0, lA0_0, chunk0, r0, c0, r1, c1);
  stage_half(A, rowBlk + 128, 0, lA1_0, chunk0, r0, c0, r1, c1);
  stage_half(B, colBlk + 0,   1, lB0_1, chunk0, r0, c0, r1, c1);
  stage_half(B, colBlk + 128, 1, lB1_1, chunk0, r0, c0, r1, c1);
  stage_half(A, rowBlk + 0,   1, lA0_1, chunk0, r0, c0, r1, c1);
  stage_half(A, rowBlk + 128, 1, lA1_1, chunk0, r0, c0, r1, c1);
  asm volatile("s_waitcnt vmcnt(8)" ::: "memory");  // tile 0 landed
  __builtin_amdgcn_s_barrier();

  bf16x8 bA[4][2], bB[4][2];
#pragma unroll
  for (int n = 0; n < 4; ++n) {
    bA[n][0] = ldsRd(myB_0, brow + n * 16 + fr, fk * 16);
    bA[n][1] = ldsRd(myB_0, brow + n * 16 + fr, 64 + fk * 16);
  }
  asm volatile("s_waitcnt lgkmcnt(0)" ::: "memory");
  __builtin_amdgcn_s_barrier();  // fence pre-reads before ph1's B-slot stage

  f32x4 acc[8][4] = {};

#pragma unroll 1
  for (int i = 0; i < (NT - 2) / 2; ++i) {
    const int t = 2 * i;
    ktile<8, 8, true, true>(A, B, rowBlk, colBlk, t,
        lA0_0, lA1_0, lB0_0, lB1_0, myB_1, myA_0, brow,
        bA, bB, acc, fr, fk, chunk0, r0, c0, r1, c1);
    ktile<8, 8, true, true>(A, B, rowBlk, colBlk, t + 1,
        lA0_1, lA1_1, lB0_1, lB1_1, myB_0, myA_1, brow,
        bB, bA, acc, fr, fk, chunk0, r0, c0, r1, c1);
  }
  // peel: tiles NT-2, NT-1 (no staging; drain counted 4 -> 0)
  ktile<4, 0, false, true>(A, B, rowBlk, colBlk, NT - 2,
      lA0_0, lA1_0, lB0_0, lB1_0, myB_1, myA_0, brow,
      bA, bB, acc, fr, fk, chunk0, r0, c0, r1, c1);
  ktile<-1, -1, false, false>(A, B, rowBlk, colBlk, NT - 1,
      lA0_1, lA1_1, lB0_1, lB1_1, myB_0, myA_1, brow,
      bB, bA, acc, fr, fk, chunk0, r0, c0, r1, c1);

  // ---- epilogue: y = acc*scale + bias; C/D: col=lane&15, row=(lane>>4)*4+j
  const float s = scale[0];
#pragma unroll
  for (int n = 0; n < 4; ++n) {
    const int col = colBlk + wn * 64 + n * 16 + fr;
    const float bv = bias[col];
#pragma unroll
    for (int m = 0; m < 8; ++m) {
      const int row = rowBlk + wm * 128 + m * 16 + fk * 4;
#pragma unroll
      for (int j = 0; j < 4; ++j)
        C[(size_t)(row + j) * OUTF + col] = acc[m][n][j] * s + bv;
    }
  }
}

// ---------------- fallback: R1 128x128 m97-structure GEMM -------------------
__global__ __launch_bounds__(256) void l2b_gemm(
    const ushort_t* __restrict__ A, const ushort_t* __restrict__ B,
    const float* __restrict__ scale, const float* __restrict__ bias,
    float* __restrict__ C) {
  constexpr int K = INF;
  constexpr int N = OUTF;
  __shared__ __align__(16) ushort_t ldsA[128 * 32];
  __shared__ __align__(16) ushort_t ldsB[128 * 32];
  const int tid = threadIdx.x;
  const int lane = tid & 63;
  const int wid = tid >> 6;
  const int wm = wid >> 1, wn = wid & 1;
  const int bm = blockIdx.x >> 5, bn = blockIdx.x & 31;
  const int row0 = bm * 128, col0 = bn * 128;
  const int lr = lane >> 4, lc = lane & 15;
  f32x4 acc[4][4] = {};
  for (int k0 = 0; k0 < K; k0 += 32) {
#pragma unroll
    for (int i = 0; i < 2; ++i) {
      const int idx = i * 256 + tid;
      const int r = idx >> 2;
      const int c = (idx & 3) * 8;
      ushort_t* lbaseA = ldsA + i * 2048 + wid * 512;
      ushort_t* lbaseB = ldsB + i * 2048 + wid * 512;
      gload_lds16(A + (size_t)(row0 + r) * K + (k0 + c), lbaseA);
      gload_lds16(B + (size_t)(col0 + r) * K + (k0 + c), lbaseB);
    }
    __syncthreads();
    bf16x8 af[4], bfr[4];
#pragma unroll
    for (int m = 0; m < 4; ++m)
      af[m] = *reinterpret_cast<const bf16x8*>(
          &ldsA[(wm * 64 + m * 16 + lc) * 32 + lr * 8]);
#pragma unroll
    for (int n = 0; n < 4; ++n)
      bfr[n] = *reinterpret_cast<const bf16x8*>(
          &ldsB[(wn * 64 + n * 16 + lc) * 32 + lr * 8]);
#pragma unroll
    for (int m = 0; m < 4; ++m)
#pragma unroll
      for (int n = 0; n < 4; ++n)
        acc[m][n] = mfma(af[m], bfr[n], acc[m][n]);
    __syncthreads();
  }
  const float s = scale[0];
#pragma unroll
  for (int n = 0; n < 4; ++n) {
    const int col = col0 + wn * 64 + n * 16 + lc;
    const float bv = bias[col];
#pragma unroll
    for (int m = 0; m < 4; ++m) {
      const int row = row0 + wm * 64 + m * 16 + lr * 4;
#pragma unroll
      for (int i = 0; i < 4; ++i)
        C[(size_t)(row + i) * N + col] = acc[m][n][i] * s + bv;
    }
  }
}

__global__ void l2b_naive(const float* __restrict__ x, const int* __restrict__ w,
                          const float* __restrict__ scale,
                          const float* __restrict__ bias,
                          float* __restrict__ out) {
  const int o = blockIdx.x * blockDim.x + threadIdx.x;
  if (o >= TOKENS * OUTF) return;
  const int t = o / OUTF;
  const int n = o - t * OUTF;
  const float* xr = x + (size_t)t * INF;
  const int* wr = w + (size_t)n * INF;
  float acc = 0.f;
  for (int k = 0; k < INF; ++k) acc += xr[k] * (float)wr[k];
  out[o] = acc * scale[0] + bias[n];
}

extern "C" void kernel_launch(void* const* d_in, const int* in_sizes, int n_in,
                              void* d_out, int out_size, void* d_ws, size_t ws_size,
                              hipStream_t stream) {
  const float* x     = (const float*)d_in[0];
  const int*   wq    = (const int*)d_in[1];
  const float* scale = (const float*)d_in[2];
  const float* bias  = (const float*)d_in[3];
  float* out = (float*)d_out;

  const size_t xbytes = (size_t)TOKENS * INF * 2;
  const size_t wbytes = (size_t)OUTF * INF * 2;

  if (ws_size >= xbytes + wbytes) {
    unsigned short* xb = (unsigned short*)d_ws;
    unsigned short* wb = (unsigned short*)((char*)d_ws + xbytes);
    l2b_conv_x<<<2048, 256, 0, stream>>>(x, xb, TOKENS * INF / 4);
    l2b_conv_w<<<2048, 256, 0, stream>>>(wq, wb, OUTF * INF / 4);

    hipError_t e = hipFuncSetAttribute(
        reinterpret_cast<const void*>(l2b_gemm8),
        hipFuncAttributeMaxDynamicSharedMemorySize, 131072);
    if (e == hipSuccess) {
      l2b_gemm8<<<dim3((TOKENS / 256) * (OUTF / 256)), 512, 131072, stream>>>(
          xb, wb, scale, bias, out);
    } else {
      l2b_gemm<<<dim3((TOKENS / 128) * (OUTF / 128)), 256, 0, stream>>>(
          xb, wb, scale, bias, out);
    }
  } else {
    l2b_naive<<<(TOKENS * OUTF + 255) / 256, 256, 0, stream>>>(
        x, wq, scale, bias, out);
  }
}

// Round 3
// 263.647 us; speedup vs baseline: 4.9869x; 4.9869x over previous
//
#include <hip/hip_runtime.h>
#include <stdint.h>

#define TOKENS 8192
#define INF    4096
#define OUTF   4096
#define NT     64   // K-tiles of BK=64

typedef __bf16 bf16x8 __attribute__((ext_vector_type(8)));
typedef float  f32x4  __attribute__((ext_vector_type(4)));
typedef unsigned short ushort_t;

// ---------- fp32 -> bf16 (RNE) ----------
__device__ __forceinline__ unsigned short f2bf(float f) {
  union { float f; unsigned int u; } v;
  v.f = f;
  unsigned int r = v.u + 0x7fffu + ((v.u >> 16) & 1u);
  return (unsigned short)(r >> 16);
}

__global__ void l2b_conv_x(const float* __restrict__ x,
                           unsigned short* __restrict__ xb, int n4) {
  int idx = blockIdx.x * blockDim.x + threadIdx.x;
  int stride = gridDim.x * blockDim.x;
  for (int i = idx; i < n4; i += stride) {
    float4 v = reinterpret_cast<const float4*>(x)[i];
    ushort4 o;
    o.x = f2bf(v.x); o.y = f2bf(v.y); o.z = f2bf(v.z); o.w = f2bf(v.w);
    reinterpret_cast<ushort4*>(xb)[i] = o;
  }
}

__global__ void l2b_conv_w(const int* __restrict__ w,
                           unsigned short* __restrict__ wb, int n4) {
  int idx = blockIdx.x * blockDim.x + threadIdx.x;
  int stride = gridDim.x * blockDim.x;
  for (int i = idx; i < n4; i += stride) {
    int4 v = reinterpret_cast<const int4*>(w)[i];
    ushort4 o;  // {-2,-1,0,1}: exact in bf16
    o.x = f2bf((float)v.x); o.y = f2bf((float)v.y);
    o.z = f2bf((float)v.z); o.w = f2bf((float)v.w);
    reinterpret_cast<ushort4*>(wb)[i] = o;
  }
}

// ---------- async global->LDS, 16B/lane (dest = wave base + lane*16) ---------
__device__ __forceinline__ void gload_lds16(const ushort_t* g, ushort_t* l) {
  auto gp = reinterpret_cast<__attribute__((address_space(1))) unsigned int*>(
      reinterpret_cast<uintptr_t>(g));
  auto lp = reinterpret_cast<__attribute__((address_space(3))) unsigned int*>(
      reinterpret_cast<uintptr_t>(l));
  __builtin_amdgcn_global_load_lds(gp, lp, 16, 0, 0);
}

// ---------- LDS half-slot [128 rows][8 chunks of 16B], chunk ^= (row&7) ------
__device__ __forceinline__ bf16x8 ldsRd(const ushort_t* slot, int row, int chunk) {
  const int off = (row << 7) + ((chunk ^ (row & 7)) << 4);  // bytes
  return *reinterpret_cast<const bf16x8*>(
      reinterpret_cast<const char*>(slot) + off);
}

// stage one 128x64 half-tile: 2 gloads/thread, linear LDS dest,
// inverse-swizzled per-lane global source (ge0/ge1 in elements)
__device__ __forceinline__ void stage_half(const ushort_t* __restrict__ src,
                                           ushort_t* slot, int wid,
                                           int ge0, int ge1) {
  gload_lds16(src + ge0, slot + wid * 512);
  gload_lds16(src + ge1, slot + 4096 + wid * 512);
}

__device__ __forceinline__ f32x4 mfma(bf16x8 a, bf16x8 b, f32x4 c) {
  return __builtin_amdgcn_mfma_f32_16x16x32_bf16(a, b, c, 0, 0, 0);
}

template <int N>
__device__ __forceinline__ void vmwait() {
  if constexpr (N == 4)      asm volatile("s_waitcnt vmcnt(4)" ::: "memory");
  else if constexpr (N == 0) asm volatile("s_waitcnt vmcnt(0)" ::: "memory");
}

#define PHASE_SYNC()                                            \
  __builtin_amdgcn_s_barrier();                                 \
  asm volatile("s_waitcnt lgkmcnt(0)" ::: "memory");            \
  __builtin_amdgcn_sched_barrier(0);                            \
  __builtin_amdgcn_s_setprio(1)

#define PHASE_END() __builtin_amdgcn_s_setprio(0)

// ---------------- one K-tile: 4 phases, 16 MFMA each -------------------------
// reads: ph1 (A0,B0) -> acc[0..3][0..1]; ph2 (A0,B1) -> acc[0..3][2..3];
//        ph3 (A1,B1) -> acc[4..7][2..3]; ph4 (A1,B0) -> acc[4..7][0..1]
// stages: ph1 A1(t+1)->oA1; ph2 B0(t+1)->oB0; ph3 A0(t+2)->rA0; ph4 B1(t+2)->rB1
template <int VMB, bool STG1, bool STG2>
__device__ __forceinline__ void ktile(
    const ushort_t* __restrict__ A, const ushort_t* __restrict__ B,
    int rowBlk, int colBlk, int t,
    ushort_t* rA0, ushort_t* rA1, ushort_t* rB0, ushort_t* rB1,
    ushort_t* oA1, ushort_t* oB0,
    f32x4 (&acc)[8][4], int ar, int br, int fk, int wid, int ge0, int ge1) {
  bf16x8 a[4][2], b[2][2];
  // ---- phase 1 ----
#pragma unroll
  for (int m = 0; m < 4; ++m) {
    a[m][0] = ldsRd(rA0, ar + m * 16, fk);
    a[m][1] = ldsRd(rA0, ar + m * 16, 4 + fk);
  }
#pragma unroll
  for (int n = 0; n < 2; ++n) {
    b[n][0] = ldsRd(rB0, br + n * 16, fk);
    b[n][1] = ldsRd(rB0, br + n * 16, 4 + fk);
  }
  if (STG1)
    stage_half(A + (size_t)(rowBlk + 128) * INF + (t + 1) * 64, oA1, wid, ge0, ge1);
  PHASE_SYNC();
#pragma unroll
  for (int m = 0; m < 4; ++m)
#pragma unroll
    for (int n = 0; n < 2; ++n) {
      acc[m][n] = mfma(a[m][0], b[n][0], acc[m][n]);
      acc[m][n] = mfma(a[m][1], b[n][1], acc[m][n]);
    }
  PHASE_END();
  __builtin_amdgcn_s_barrier();
  // ---- phase 2 ----
#pragma unroll
  for (int n = 0; n < 2; ++n) {
    b[n][0] = ldsRd(rB1, br + n * 16, fk);
    b[n][1] = ldsRd(rB1, br + n * 16, 4 + fk);
  }
  if (STG1)
    stage_half(B + (size_t)colBlk * INF + (t + 1) * 64, oB0, wid, ge0, ge1);
  PHASE_SYNC();
#pragma unroll
  for (int m = 0; m < 4; ++m)
#pragma unroll
    for (int n = 0; n < 2; ++n) {
      acc[m][2 + n] = mfma(a[m][0], b[n][0], acc[m][2 + n]);
      acc[m][2 + n] = mfma(a[m][1], b[n][1], acc[m][2 + n]);
    }
  PHASE_END();
  __builtin_amdgcn_s_barrier();
  // ---- phase 3 (B1 frags reused from regs) ----
#pragma unroll
  for (int m = 0; m < 4; ++m) {
    a[m][0] = ldsRd(rA1, ar + m * 16, fk);
    a[m][1] = ldsRd(rA1, ar + m * 16, 4 + fk);
  }
  if (STG2)
    stage_half(A + (size_t)rowBlk * INF + (t + 2) * 64, rA0, wid, ge0, ge1);
  PHASE_SYNC();
#pragma unroll
  for (int m = 0; m < 4; ++m)
#pragma unroll
    for (int n = 0; n < 2; ++n) {
      acc[4 + m][2 + n] = mfma(a[m][0], b[n][0], acc[4 + m][2 + n]);
      acc[4 + m][2 + n] = mfma(a[m][1], b[n][1], acc[4 + m][2 + n]);
    }
  PHASE_END();
  __builtin_amdgcn_s_barrier();
  // ---- phase 4 (re-read B0) ----
#pragma unroll
  for (int n = 0; n < 2; ++n) {
    b[n][0] = ldsRd(rB0, br + n * 16, fk);
    b[n][1] = ldsRd(rB0, br + n * 16, 4 + fk);
  }
  if (STG2)
    stage_half(B + (size_t)(colBlk + 128) * INF + (t + 2) * 64, rB1, wid, ge0, ge1);
  PHASE_SYNC();
#pragma unroll
  for (int m = 0; m < 4; ++m)
#pragma unroll
    for (int n = 0; n < 2; ++n) {
      acc[4 + m][n] = mfma(a[m][0], b[n][0], acc[4 + m][n]);
      acc[4 + m][n] = mfma(a[m][1], b[n][1], acc[4 + m][n]);
    }
  PHASE_END();
  if (VMB >= 0) vmwait<VMB >= 0 ? VMB : 0>();
  __builtin_amdgcn_s_barrier();
}

// ---------------- 256x256 8-phase GEMM: C[t][o] = A[t][:] . B[o][:] ----------
__global__ __launch_bounds__(512, 2) void l2b_gemm8(
    const ushort_t* __restrict__ A, const ushort_t* __restrict__ B,
    const float* __restrict__ scale, const float* __restrict__ bias,
    float* __restrict__ C) {
  extern __shared__ ushort_t smem[];  // 128 KiB = 8 half-slots of 16 KiB
  // A slots: [parity][half], then B slots
  ushort_t* sA00 = smem;              ushort_t* sA01 = smem + 8192;
  ushort_t* sA10 = smem + 16384;      ushort_t* sA11 = smem + 24576;
  ushort_t* sB00 = smem + 32768;      ushort_t* sB01 = smem + 40960;
  ushort_t* sB10 = smem + 49152;      ushort_t* sB11 = smem + 57344;

  const int tid  = threadIdx.x;
  const int lane = tid & 63;
  const int wid  = tid >> 6;              // 0..7
  const int wm = wid >> 2, wn = wid & 3;  // 2x4 wave grid
  const int fr = lane & 15, fk = lane >> 4;
  const int ar = wm * 64 + fr;            // a-frag row within half
  const int br = wn * 32 + fr;            // b-frag row within half

  // XCD-aware swizzle (nwg=512, divisible by 8)
  const int bid = (int)blockIdx.x;
  const int idx = (bid & 7) * 64 + (bid >> 3);
  const int bm = idx >> 4, bn = idx & 15;
  const int rowBlk = bm * 256, colBlk = bn * 256;

  // inverse-swizzled per-lane global element offsets for the 2 staging rounds
  const int ob0 = wid * 1024 + lane * 16;       // byte off in half-slot, round 0
  const int ob1 = 8192 + ob0;                   // round 1
  const int r0 = ob0 >> 7, c0 = (ob0 >> 4) & 7;
  const int r1 = ob1 >> 7, c1 = (ob1 >> 4) & 7;
  const int ge0 = r0 * INF + ((c0 ^ (r0 & 7)) << 3);
  const int ge1 = r1 * INF + ((c1 ^ (r1 & 7)) << 3);

  // ---- prologue: steady-state stream order A0(0),B1(0),A1(0),B0(0),A0(1),B1(1)
  stage_half(A + (size_t)rowBlk * INF,               sA00, wid, ge0, ge1);
  stage_half(B + (size_t)(colBlk + 128) * INF,       sB01, wid, ge0, ge1);
  stage_half(A + (size_t)(rowBlk + 128) * INF,       sA01, wid, ge0, ge1);
  stage_half(B + (size_t)colBlk * INF,               sB00, wid, ge0, ge1);
  stage_half(A + (size_t)rowBlk * INF + 64,          sA10, wid, ge0, ge1);
  stage_half(B + (size_t)(colBlk + 128) * INF + 64,  sB11, wid, ge0, ge1);
  asm volatile("s_waitcnt vmcnt(4)" ::: "memory");   // tile 0 landed
  __builtin_amdgcn_s_barrier();

  f32x4 acc[8][4] = {};

#pragma unroll 1
  for (int i = 0; i < 31; ++i) {                     // tiles 0..61
    const int t = 2 * i;
    ktile<4, true, true>(A, B, rowBlk, colBlk, t,
        sA00, sA01, sB00, sB01, sA11, sB10,
        acc, ar, br, fk, wid, ge0, ge1);
    ktile<4, true, true>(A, B, rowBlk, colBlk, t + 1,
        sA10, sA11, sB10, sB11, sA01, sB00,
        acc, ar, br, fk, wid, ge0, ge1);
  }
  // tile 62 (parity 0): stage only t+1=63; drain vmcnt to 0 at boundary
  ktile<0, true, false>(A, B, rowBlk, colBlk, 62,
      sA00, sA01, sB00, sB01, sA11, sB10,
      acc, ar, br, fk, wid, ge0, ge1);
  // tile 63 (parity 1): compute only
  ktile<-1, false, false>(A, B, rowBlk, colBlk, 63,
      sA10, sA11, sB10, sB11, sA01, sB00,
      acc, ar, br, fk, wid, ge0, ge1);

  // ---- epilogue: y = acc*scale + bias; C/D: col=lane&15, row=(lane>>4)*4+j
  const float s = scale[0];
#pragma unroll
  for (int ni = 0; ni < 4; ++ni) {
    const int nh = ni >> 1, n = ni & 1;
    const int col = colBlk + nh * 128 + wn * 32 + n * 16 + fr;
    const float bv = bias[col];
#pragma unroll
    for (int mi = 0; mi < 8; ++mi) {
      const int mh = mi >> 2, m = mi & 3;
      const int row = rowBlk + mh * 128 + wm * 64 + m * 16 + fk * 4;
#pragma unroll
      for (int j = 0; j < 4; ++j)
        C[(size_t)(row + j) * OUTF + col] = acc[mi][ni][j] * s + bv;
    }
  }
}

// ---------------- fallback: R1 128x128 m97-structure GEMM -------------------
__global__ __launch_bounds__(256) void l2b_gemm(
    const ushort_t* __restrict__ A, const ushort_t* __restrict__ B,
    const float* __restrict__ scale, const float* __restrict__ bias,
    float* __restrict__ C) {
  constexpr int K = INF;
  constexpr int N = OUTF;
  __shared__ __align__(16) ushort_t ldsA[128 * 32];
  __shared__ __align__(16) ushort_t ldsB[128 * 32];
  const int tid = threadIdx.x;
  const int lane = tid & 63;
  const int wid = tid >> 6;
  const int wm = wid >> 1, wn = wid & 1;
  const int bm = blockIdx.x >> 5, bn = blockIdx.x & 31;
  const int row0 = bm * 128, col0 = bn * 128;
  const int lr = lane >> 4, lc = lane & 15;
  f32x4 acc[4][4] = {};
  for (int k0 = 0; k0 < K; k0 += 32) {
#pragma unroll
    for (int i = 0; i < 2; ++i) {
      const int idx = i * 256 + tid;
      const int r = idx >> 2;
      const int c = (idx & 3) * 8;
      ushort_t* lbaseA = ldsA + i * 2048 + wid * 512;
      ushort_t* lbaseB = ldsB + i * 2048 + wid * 512;
      gload_lds16(A + (size_t)(row0 + r) * K + (k0 + c), lbaseA);
      gload_lds16(B + (size_t)(col0 + r) * K + (k0 + c), lbaseB);
    }
    __syncthreads();
    bf16x8 af[4], bfr[4];
#pragma unroll
    for (int m = 0; m < 4; ++m)
      af[m] = *reinterpret_cast<const bf16x8*>(
          &ldsA[(wm * 64 + m * 16 + lc) * 32 + lr * 8]);
#pragma unroll
    for (int n = 0; n < 4; ++n)
      bfr[n] = *reinterpret_cast<const bf16x8*>(
          &ldsB[(wn * 64 + n * 16 + lc) * 32 + lr * 8]);
#pragma unroll
    for (int m = 0; m < 4; ++m)
#pragma unroll
      for (int n = 0; n < 4; ++n)
        acc[m][n] = mfma(af[m], bfr[n], acc[m][n]);
    __syncthreads();
  }
  const float s = scale[0];
#pragma unroll
  for (int n = 0; n < 4; ++n) {
    const int col = col0 + wn * 64 + n * 16 + lc;
    const float bv = bias[col];
#pragma unroll
    for (int m = 0; m < 4; ++m) {
      const int row = row0 + wm * 64 + m * 16 + lr * 4;
#pragma unroll
      for (int i = 0; i < 4; ++i)
        C[(size_t)(row + i) * N + col] = acc[m][n][i] * s + bv;
    }
  }
}

__global__ void l2b_naive(const float* __restrict__ x, const int* __restrict__ w,
                          const float* __restrict__ scale,
                          const float* __restrict__ bias,
                          float* __restrict__ out) {
  const int o = blockIdx.x * blockDim.x + threadIdx.x;
  if (o >= TOKENS * OUTF) return;
  const int t = o / OUTF;
  const int n = o - t * OUTF;
  const float* xr = x + (size_t)t * INF;
  const int* wr = w + (size_t)n * INF;
  float acc = 0.f;
  for (int k = 0; k < INF; ++k) acc += xr[k] * (float)wr[k];
  out[o] = acc * scale[0] + bias[n];
}

extern "C" void kernel_launch(void* const* d_in, const int* in_sizes, int n_in,
                              void* d_out, int out_size, void* d_ws, size_t ws_size,
                              hipStream_t stream) {
  const float* x     = (const float*)d_in[0];
  const int*   wq    = (const int*)d_in[1];
  const float* scale = (const float*)d_in[2];
  const float* bias  = (const float*)d_in[3];
  float* out = (float*)d_out;

  const size_t xbytes = (size_t)TOKENS * INF * 2;
  const size_t wbytes = (size_t)OUTF * INF * 2;

  if (ws_size >= xbytes + wbytes) {
    unsigned short* xb = (unsigned short*)d_ws;
    unsigned short* wb = (unsigned short*)((char*)d_ws + xbytes);
    l2b_conv_x<<<2048, 256, 0, stream>>>(x, xb, TOKENS * INF / 4);
    l2b_conv_w<<<2048, 256, 0, stream>>>(wq, wb, OUTF * INF / 4);

    hipError_t e = hipFuncSetAttribute(
        reinterpret_cast<const void*>(l2b_gemm8),
        hipFuncAttributeMaxDynamicSharedMemorySize, 131072);
    if (e == hipSuccess) {
      l2b_gemm8<<<dim3((TOKENS / 256) * (OUTF / 256)), 512, 131072, stream>>>(
          xb, wb, scale, bias, out);
    } else {
      l2b_gemm<<<dim3((TOKENS / 128) * (OUTF / 128)), 256, 0, stream>>>(
          xb, wb, scale, bias, out);
    }
  } else {
    l2b_naive<<<(TOKENS * OUTF + 255) / 256, 256, 0, stream>>>(
        x, wq, scale, bias, out);
  }
}